// Round 2
// baseline (183.551 us; speedup 1.0000x reference)
//
#include <hip/hip_runtime.h>

// DCN CrossLayer: B=16384, F=1024, L=3, fp32.
// Algebraic expansion of the 3-layer recurrence (verified against reference):
//   d_j  = x0 . w_j    (per-row)       t01=b0.w1  t02=b0.w2  t12=b1.w2 (global)
//   a1 = 1+d0;  s1 = a1*d1 + t01;  a2 = a1+s1;  s2 = a2*d2 + t02+t12
//   out = x0*(a2+s2) + (b0+b1+b2)
//
// v3: 2 rows per wave (v2 post-mortem: R=4 cut the grid to 4096 waves =
// 16/CU nominal, measured 25% occupancy, 2.9 TB/s -> latency-bound; the
// amortization won the instruction battle but lost the TLP war).
// R=2 keeps 2x amortization of the broadcast w/b loads and the butterfly
// (mem inst/row 40->22, shuffle-adds/row 36->27 vs R=1) while restoring
// 8192 waves = 32 waves/CU = full single-generation residency.
// VGPR budget ~60 (32 x-regs + 12 w transients + 9 partials + addr);
// __launch_bounds__(256,8) pins the compiler at <=64 VGPR so 8 waves/SIMD
// actually materialize. Memory-bound: ~128 MiB mandatory HBM traffic.

constexpr int B = 16384;
constexpr int F = 1024;                 // 256 float4 per row = 4 chunks of 64 lanes
constexpr int ROWS_PER_WAVE = 2;
constexpr int WAVES = 4;
constexpr int ROWS_PER_BLOCK = ROWS_PER_WAVE * WAVES;  // 8
constexpr int BLOCK = 64 * WAVES;       // 256 threads

__global__ __launch_bounds__(BLOCK, 8) void cross_layer_kernel(
    const float* __restrict__ x,        // [B, F]
    const float* __restrict__ kernels,  // [3, F]
    const float* __restrict__ bias,     // [3, F]
    float* __restrict__ out)            // [B, F]
{
    const int lane = threadIdx.x & 63;
    const int wave = threadIdx.x >> 6;
    const int row0 = blockIdx.x * ROWS_PER_BLOCK + wave * ROWS_PER_WAVE;

    const float4* w0v = (const float4*)(kernels);
    const float4* w1v = (const float4*)(kernels + F);
    const float4* w2v = (const float4*)(kernels + 2 * F);
    const float4* b0v = (const float4*)(bias);
    const float4* b1v = (const float4*)(bias + F);
    const float4* b2v = (const float4*)(bias + 2 * F);

    // Front-load both x rows (8 coalesced 16B loads; x read exactly once).
    float4 xr[ROWS_PER_WAVE][4];
#pragma unroll
    for (int r = 0; r < ROWS_PER_WAVE; ++r) {
        const float4* xrow = (const float4*)(x + (size_t)(row0 + r) * F);
#pragma unroll
        for (int c = 0; c < 4; ++c) xr[r][c] = xrow[c * 64 + lane];
    }

    // Per-row dot partials d[r][j] = x_r . w_j (6 accumulators).
    float d[ROWS_PER_WAVE][3];
#pragma unroll
    for (int r = 0; r < ROWS_PER_WAVE; ++r)
        d[r][0] = d[r][1] = d[r][2] = 0.f;

#pragma unroll
    for (int c = 0; c < 4; ++c) {
        const int i = c * 64 + lane;
        const float4 w0 = w0v[i];
        const float4 w1 = w1v[i];
        const float4 w2 = w2v[i];
#pragma unroll
        for (int r = 0; r < ROWS_PER_WAVE; ++r) {
            const float4 xv = xr[r][c];
            d[r][0] = fmaf(xv.x, w0.x, d[r][0]);
            d[r][0] = fmaf(xv.y, w0.y, d[r][0]);
            d[r][0] = fmaf(xv.z, w0.z, d[r][0]);
            d[r][0] = fmaf(xv.w, w0.w, d[r][0]);

            d[r][1] = fmaf(xv.x, w1.x, d[r][1]);
            d[r][1] = fmaf(xv.y, w1.y, d[r][1]);
            d[r][1] = fmaf(xv.z, w1.z, d[r][1]);
            d[r][1] = fmaf(xv.w, w1.w, d[r][1]);

            d[r][2] = fmaf(xv.x, w2.x, d[r][2]);
            d[r][2] = fmaf(xv.y, w2.y, d[r][2]);
            d[r][2] = fmaf(xv.z, w2.z, d[r][2]);
            d[r][2] = fmaf(xv.w, w2.w, d[r][2]);
        }
    }

    // Row-independent bias-kernel dots (L1-resident re-reads; kept out of
    // the main loop to hold peak register pressure under 64 VGPR).
    float t01 = 0.f, t02 = 0.f, t12 = 0.f;
#pragma unroll
    for (int c = 0; c < 4; ++c) {
        const int i = c * 64 + lane;
        const float4 w1 = w1v[i];
        const float4 w2 = w2v[i];
        const float4 b0 = b0v[i];
        const float4 b1 = b1v[i];
        t01 = fmaf(b0.x, w1.x, t01); t01 = fmaf(b0.y, w1.y, t01);
        t01 = fmaf(b0.z, w1.z, t01); t01 = fmaf(b0.w, w1.w, t01);
        t02 = fmaf(b0.x, w2.x, t02); t02 = fmaf(b0.y, w2.y, t02);
        t02 = fmaf(b0.z, w2.z, t02); t02 = fmaf(b0.w, w2.w, t02);
        t12 = fmaf(b1.x, w2.x, t12); t12 = fmaf(b1.y, w2.y, t12);
        t12 = fmaf(b1.z, w2.z, t12); t12 = fmaf(b1.w, w2.w, t12);
    }

    // Single interleaved 9-value butterfly: 6 row-dots + 3 t-terms.
    // All 9 shuffles per step are independent -> DS latency paid ~once/step,
    // amortized over 2 rows.
    float p[9] = { d[0][0], d[0][1], d[0][2],
                   d[1][0], d[1][1], d[1][2],
                   t01, t02, t12 };
#pragma unroll
    for (int off = 32; off >= 1; off >>= 1) {
#pragma unroll
        for (int k = 0; k < 9; ++k) p[k] += __shfl_xor(p[k], off, 64);
    }

    // Scalar recurrences (all lanes hold the full sums).
    const float tsum = p[7] + p[8];     // t02 + t12
    float S[ROWS_PER_WAVE];
#pragma unroll
    for (int r = 0; r < ROWS_PER_WAVE; ++r) {
        const float a1 = 1.f + p[3 * r + 0];
        const float s1 = fmaf(a1, p[3 * r + 1], p[6]);
        const float a2 = a1 + s1;
        const float s2 = fmaf(a2, p[3 * r + 2], tsum);
        S[r] = a2 + s2;
    }

    // Epilogue: out = x0*S + (b0+b1+b2). b re-read once per wave (L1-hit),
    // bias sum shared across both rows.
#pragma unroll
    for (int c = 0; c < 4; ++c) {
        const int i = c * 64 + lane;
        const float4 b0 = b0v[i];
        const float4 b1 = b1v[i];
        const float4 b2 = b2v[i];
        float4 bs;
        bs.x = b0.x + b1.x + b2.x;
        bs.y = b0.y + b1.y + b2.y;
        bs.z = b0.z + b1.z + b2.z;
        bs.w = b0.w + b1.w + b2.w;
#pragma unroll
        for (int r = 0; r < ROWS_PER_WAVE; ++r) {
            float4 o;
            o.x = fmaf(xr[r][c].x, S[r], bs.x);
            o.y = fmaf(xr[r][c].y, S[r], bs.y);
            o.z = fmaf(xr[r][c].z, S[r], bs.z);
            o.w = fmaf(xr[r][c].w, S[r], bs.w);
            ((float4*)(out + (size_t)(row0 + r) * F))[i] = o;
        }
    }
}

extern "C" void kernel_launch(void* const* d_in, const int* in_sizes, int n_in,
                              void* d_out, int out_size, void* d_ws, size_t ws_size,
                              hipStream_t stream) {
    const float* x       = (const float*)d_in[0];
    const float* kernels = (const float*)d_in[1];
    const float* bias    = (const float*)d_in[2];
    float* out           = (float*)d_out;

    dim3 grid(B / ROWS_PER_BLOCK);  // 2048 blocks
    dim3 block(BLOCK);              // 256 threads = 4 waves
    cross_layer_kernel<<<grid, block, 0, stream>>>(x, kernels, bias, out);
}

// Round 3
// 120.807 us; speedup vs baseline: 1.5194x; 1.5194x over previous
//
#include <hip/hip_runtime.h>

// DCN CrossLayer: B=16384, F=1024, L=3, fp32.
// Algebraic expansion of the 3-layer recurrence (verified vs reference):
//   d_j  = x0 . w_j  (per-row)     t01=b0.w1  t02=b0.w2  t12=b1.w2 (GLOBAL)
//   a1 = 1+d0;  s1 = a1*d1 + t01;  a2 = a1+s1;  s2 = a2*d2 + t02+t12
//   out = x0*(a2+s2) + (b0+b1+b2)
//
// v4: R=1 (v1's proven full-residency structure: 16384 waves, 4096 blocks)
// + a 1-block prep kernel hoisting ALL row-independent work into d_ws:
//   ws[0..2]  = t01, t02, t12        (3 scalar dots)
//   ws[4..]   = bias_sum[1024]       (b0+b1+b2)
// Per-row cost drops 40 -> 24 float4 mem insts and the butterfly 6 -> 3
// values (36 -> 18 shuffles). No forced launch-bounds min (v3 post-mortem:
// __launch_bounds__(256,8) forced a 64-VGPR cap -> spilled xr to scratch,
// VGPR_Count=32, +160MB scratch HBM traffic, 96us). Live set here ~45 VGPR
// -> 8 waves/SIMD materialize naturally.

constexpr int B = 16384;
constexpr int F = 1024;                 // 256 float4 per row = 4 chunks of 64 lanes
constexpr int WAVES = 4;
constexpr int ROWS_PER_BLOCK = WAVES;   // 1 row per wave
constexpr int BLOCK = 64 * WAVES;       // 256 threads

// ---------------------------------------------------------------- prep ----
// One block. All 256 threads: bias_sum (one float4 each, 256*4 = 1024 floats).
// Wave 0 additionally computes the three bias-kernel dots + 3-value butterfly.
__global__ __launch_bounds__(BLOCK) void prep_kernel(
    const float* __restrict__ kernels,  // [3, F]
    const float* __restrict__ bias,     // [3, F]
    float* __restrict__ ws)             // [0..2]=t01,t02,t12  [4..1027]=bias_sum
{
    const int tid = threadIdx.x;
    const float4* w1v = (const float4*)(kernels + F);
    const float4* w2v = (const float4*)(kernels + 2 * F);
    const float4* b0v = (const float4*)(bias);
    const float4* b1v = (const float4*)(bias + F);
    const float4* b2v = (const float4*)(bias + 2 * F);

    // bias_sum: thread t owns float4 index t (exactly covers F=1024).
    const float4 B0 = b0v[tid];
    const float4 B1 = b1v[tid];
    const float4 B2 = b2v[tid];
    float4 bs;
    bs.x = B0.x + B1.x + B2.x;
    bs.y = B0.y + B1.y + B2.y;
    bs.z = B0.z + B1.z + B2.z;
    bs.w = B0.w + B1.w + B2.w;
    ((float4*)(ws + 4))[tid] = bs;

    // wave 0: the three global dots.
    if (tid < 64) {
        float t01 = 0.f, t02 = 0.f, t12 = 0.f;
#pragma unroll
        for (int c = 0; c < 4; ++c) {
            const int i = c * 64 + tid;
            const float4 w1 = w1v[i];
            const float4 w2 = w2v[i];
            const float4 b0 = b0v[i];
            const float4 b1 = b1v[i];
            t01 = fmaf(b0.x, w1.x, t01); t01 = fmaf(b0.y, w1.y, t01);
            t01 = fmaf(b0.z, w1.z, t01); t01 = fmaf(b0.w, w1.w, t01);
            t02 = fmaf(b0.x, w2.x, t02); t02 = fmaf(b0.y, w2.y, t02);
            t02 = fmaf(b0.z, w2.z, t02); t02 = fmaf(b0.w, w2.w, t02);
            t12 = fmaf(b1.x, w2.x, t12); t12 = fmaf(b1.y, w2.y, t12);
            t12 = fmaf(b1.z, w2.z, t12); t12 = fmaf(b1.w, w2.w, t12);
        }
#pragma unroll
        for (int off = 32; off >= 1; off >>= 1) {
            t01 += __shfl_xor(t01, off, 64);
            t02 += __shfl_xor(t02, off, 64);
            t12 += __shfl_xor(t12, off, 64);
        }
        if (tid == 0) {
            ws[0] = t01;
            ws[1] = t02;
            ws[2] = t12;
        }
    }
}

// ---------------------------------------------------------------- main ----
__global__ __launch_bounds__(BLOCK) void cross_layer_kernel(
    const float* __restrict__ x,        // [B, F]
    const float* __restrict__ kernels,  // [3, F]
    const float* __restrict__ ws,       // prep output
    float* __restrict__ out)            // [B, F]
{
    const int lane = threadIdx.x & 63;
    const int wave = threadIdx.x >> 6;
    const int row  = blockIdx.x * ROWS_PER_BLOCK + wave;

    const float4* xrow = (const float4*)(x + (size_t)row * F);
    const float4* w0v  = (const float4*)(kernels);
    const float4* w1v  = (const float4*)(kernels + F);
    const float4* w2v  = (const float4*)(kernels + 2 * F);
    const float4* bsv  = (const float4*)(ws + 4);

    // Front-load the x row (coalesced 16B/lane; x read exactly once).
    float4 x0[4];
#pragma unroll
    for (int c = 0; c < 4; ++c) x0[c] = xrow[c * 64 + lane];

    // Uniform scalars from prep (SGPR loads).
    const float t01  = ws[0];
    const float tsum = ws[1] + ws[2];

    // 3 per-row dot partials.
    float d0 = 0.f, d1 = 0.f, d2 = 0.f;
#pragma unroll
    for (int c = 0; c < 4; ++c) {
        const int i = c * 64 + lane;
        const float4 w0 = w0v[i];
        const float4 w1 = w1v[i];
        const float4 w2 = w2v[i];
        const float4 xv = x0[c];
        d0 = fmaf(xv.x, w0.x, d0); d0 = fmaf(xv.y, w0.y, d0);
        d0 = fmaf(xv.z, w0.z, d0); d0 = fmaf(xv.w, w0.w, d0);
        d1 = fmaf(xv.x, w1.x, d1); d1 = fmaf(xv.y, w1.y, d1);
        d1 = fmaf(xv.z, w1.z, d1); d1 = fmaf(xv.w, w1.w, d1);
        d2 = fmaf(xv.x, w2.x, d2); d2 = fmaf(xv.y, w2.y, d2);
        d2 = fmaf(xv.z, w2.z, d2); d2 = fmaf(xv.w, w2.w, d2);
    }

    // Interleaved 3-value butterfly (shuffles per step independent).
#pragma unroll
    for (int off = 32; off >= 1; off >>= 1) {
        d0 += __shfl_xor(d0, off, 64);
        d1 += __shfl_xor(d1, off, 64);
        d2 += __shfl_xor(d2, off, 64);
    }

    // Scalar recurrence (all lanes hold the full sums).
    const float a1 = 1.f + d0;
    const float s1 = fmaf(a1, d1, t01);
    const float a2 = a1 + s1;
    const float s2 = fmaf(a2, d2, tsum);
    const float S  = a2 + s2;

    // Epilogue: out = x0*S + bias_sum (bias_sum L1/L2-broadcast, 4 KiB).
    float4* orow = (float4*)(out + (size_t)row * F);
#pragma unroll
    for (int c = 0; c < 4; ++c) {
        const int i = c * 64 + lane;
        const float4 bs = bsv[i];
        float4 o;
        o.x = fmaf(x0[c].x, S, bs.x);
        o.y = fmaf(x0[c].y, S, bs.y);
        o.z = fmaf(x0[c].z, S, bs.z);
        o.w = fmaf(x0[c].w, S, bs.w);
        orow[i] = o;
    }
}

extern "C" void kernel_launch(void* const* d_in, const int* in_sizes, int n_in,
                              void* d_out, int out_size, void* d_ws, size_t ws_size,
                              hipStream_t stream) {
    const float* x       = (const float*)d_in[0];
    const float* kernels = (const float*)d_in[1];
    const float* bias    = (const float*)d_in[2];
    float* out           = (float*)d_out;
    float* ws            = (float*)d_ws;   // needs 1028 floats (~4.1 KiB)

    prep_kernel<<<dim3(1), dim3(BLOCK), 0, stream>>>(kernels, bias, ws);
    cross_layer_kernel<<<dim3(B / ROWS_PER_BLOCK), dim3(BLOCK), 0, stream>>>(
        x, kernels, ws, out);
}